// Round 1
// baseline (800.076 us; speedup 1.0000x reference)
//
#include <hip/hip_runtime.h>
#include <hip/hip_bf16.h>

#define B_ROWS 16384
#define NODE_F 172
#define MEMD 128
#define NN 1000000

typedef __bf16 bf16;
typedef __bf16 bf16x8 __attribute__((ext_vector_type(8)));
typedef float f32x4 __attribute__((ext_vector_type(4)));

// weight offsets (bf16 elements) inside wb; all stored as [N][Kpad] (B^T, n-major)
#define W_EDGE_O 0        // [128][192]
#define W_MP1_O  24576    // [128][128]
#define W_MP2_O  40960    // [128][128]
#define W_IH_O   57344    // [384][128]
#define W_HH_O   106496   // [384][128]
#define W_NODE_O 155648   // [128][192]
#define W_P1_O   180224   // [128][256]
#define W_P2_O   212992   // [128][128]
#define W_L1_O   229376   // [128][256]
#define W_TOTAL  262144

__device__ __forceinline__ f32x4 mfma16(bf16x8 a, bf16x8 b, f32x4 c) {
    return __builtin_amdgcn_mfma_f32_16x16x32_bf16(a, b, c, 0, 0, 0);
}

__device__ __forceinline__ int clampid(int id) {
    return id < 0 ? 0 : (id > NN - 1 ? NN - 1 : id);
}

__device__ __forceinline__ float sigmoidf_(float x) {
    return 1.f / (1.f + __expf(-x));
}

__device__ __forceinline__ float tanhf_(float x) {
    return 1.f - 2.f / (__expf(2.f * x) + 1.f);
}

// compiler-only memory fence: same-wave LDS write->read is ordered in HW
// (per-wave DS ops execute in program order); this just pins compiler order.
__device__ __forceinline__ void wavefence() { asm volatile("" ::: "memory"); }

// One wave: 16 rows x NT n-tiles (16 cols each), K = KSTEPS*32.
template<int NT, int KSTEPS>
__device__ __forceinline__ void gemm_wave(const bf16* Alds, int lda,
                                          const bf16* Bw, int ldb,
                                          f32x4* acc)
{
    int lane = threadIdx.x & 63;
    int p = lane & 15, q = lane >> 4;
    const bf16* ap  = Alds + p * lda + q * 8;
    const bf16* bp0 = Bw + (long)p * ldb + q * 8;
#pragma unroll
    for (int kt = 0; kt < KSTEPS; ++kt) {
        bf16x8 a = *(const bf16x8*)(ap + kt * 32);
#pragma unroll
        for (int j = 0; j < NT; ++j) {
            bf16x8 b = *(const bf16x8*)(bp0 + (long)j * 16 * ldb + kt * 32);
            acc[j] = mfma16(a, b, acc[j]);
        }
    }
}

// Register-resident GRU for one wave's 16 rows: computes all 8 output col-tiles;
// for each tile the 6 accumulators (gi_r/z/n, gh_r/z/n) live in VGPRs and the
// GRU elementwise is applied directly -> newmem, no LDS round-trip.
template<int KSTEPS>
__device__ __forceinline__ void gru_tiles(
    const bf16* ApSlab, const bf16* AcSlab, int lda,
    const bf16* wih, const bf16* whh,
    const float* __restrict__ b_ih, const float* __restrict__ b_hh,
    const float* const* hrow, const float* s4,
    float* __restrict__ outBase)
{
    int lane = threadIdx.x & 63;
    int p = lane & 15, q = lane >> 4;
    const bf16* ap = ApSlab + p * lda + q * 8;
    const bf16* ac = AcSlab + p * lda + q * 8;
#pragma unroll
    for (int j = 0; j < 8; ++j) {
        int col = j * 16 + p;
        const bf16* br = wih + (long)col * 128 + q * 8;
        const bf16* bz = br + 128 * 128;
        const bf16* bn = bz + 128 * 128;
        const bf16* cr = whh + (long)col * 128 + q * 8;
        const bf16* cz = cr + 128 * 128;
        const bf16* cn = cz + 128 * 128;
        f32x4 air = {0.f,0.f,0.f,0.f}, aiz = {0.f,0.f,0.f,0.f}, ain = {0.f,0.f,0.f,0.f};
        f32x4 ahr = {0.f,0.f,0.f,0.f}, ahz = {0.f,0.f,0.f,0.f}, ahn = {0.f,0.f,0.f,0.f};
#pragma unroll
        for (int kt = 0; kt < KSTEPS; ++kt) {
            bf16x8 a1 = *(const bf16x8*)(ap + kt * 32);
            bf16x8 a2 = *(const bf16x8*)(ac + kt * 32);
            air = mfma16(a1, *(const bf16x8*)(br + kt * 32), air);
            aiz = mfma16(a1, *(const bf16x8*)(bz + kt * 32), aiz);
            ain = mfma16(a1, *(const bf16x8*)(bn + kt * 32), ain);
            ahr = mfma16(a2, *(const bf16x8*)(cr + kt * 32), ahr);
            ahz = mfma16(a2, *(const bf16x8*)(cz + kt * 32), ahz);
            ahn = mfma16(a2, *(const bf16x8*)(cn + kt * 32), ahn);
        }
        float bir = b_ih[col], biz = b_ih[128 + col], bin = b_ih[256 + col];
        float bhr = b_hh[col], bhz = b_hh[128 + col], bhn = b_hh[256 + col];
#pragma unroll
        for (int v = 0; v < 4; ++v) {
            float rg = sigmoidf_(air[v] + bir + ahr[v] + bhr);
            float zg = sigmoidf_(aiz[v] + biz + ahz[v] + bhz);
            float ng = tanhf_(ain[v] + bin + rg * (ahn[v] + bhn));
            float h  = hrow[v][col] * s4[v];
            outBase[(q * 4 + v) * MEMD + col] = (1.f - zg) * ng + zg * h;
        }
    }
}

// ---------------- prep: init occS/occD to -1 (int4 stores) + weight cast/transpose ----------------
__global__ __launch_bounds__(256) void prep_kernel(
    const float* __restrict__ W_edge, const float* __restrict__ W_mp1,
    const float* __restrict__ W_mp2, const float* __restrict__ W_ih,
    const float* __restrict__ W_hh, const float* __restrict__ W_node,
    const float* __restrict__ W_p1, const float* __restrict__ W_p2,
    const float* __restrict__ W_l1,
    int* __restrict__ occS, int* __restrict__ occD, bf16* __restrict__ wb)
{
    int gid = blockIdx.x * 256 + threadIdx.x;
    if (gid < NN / 4) {
        int4 m1 = {-1, -1, -1, -1};
        ((int4*)occS)[gid] = m1;
        ((int4*)occD)[gid] = m1;
    }
    int t = gid;
    if (t < W_TOTAL) {
        float v;
        if (t < W_MP1_O)      { int u = t;            int n = u / 192, k = u % 192; v = (k < NODE_F) ? W_edge[k * 128 + n] : 0.f; }
        else if (t < W_MP2_O) { int u = t - W_MP1_O;  int n = u / 128, k = u % 128; v = W_mp1[k * 128 + n]; }
        else if (t < W_IH_O)  { int u = t - W_MP2_O;  int n = u / 128, k = u % 128; v = W_mp2[k * 128 + n]; }
        else if (t < W_HH_O)  { int u = t - W_IH_O;   v = W_ih[u]; }   // already [384][128] n-major
        else if (t < W_NODE_O){ int u = t - W_HH_O;   v = W_hh[u]; }
        else if (t < W_P1_O)  { int u = t - W_NODE_O; int n = u / 192, k = u % 192; v = (k < NODE_F) ? W_node[k * 128 + n] : 0.f; }
        else if (t < W_P2_O)  { int u = t - W_P1_O;   int n = u / 256, k = u % 256; v = W_p1[k * 128 + n]; }
        else if (t < W_L1_O)  { int u = t - W_P2_O;   int n = u / 128, k = u % 128; v = W_p2[k * 128 + n]; }
        else                  { int u = t - W_L1_O;   int n = u / 256, k = u % 256; v = W_l1[k * 128 + n]; }
        wb[t] = (bf16)v;
    }
}

// ---------------- fused: occ tagging + proc (3 GEMMs) + src-round GRU; barrier-free ----------------
// Each wave owns 16 rows end-to-end. LDS overlays are wave-slab-local (no cross-wave hazard).
__global__ __launch_bounds__(128) void pgs_kernel(
    const int* __restrict__ src_ids, const int* __restrict__ dst_ids,
    const float* __restrict__ ts, const float* __restrict__ edgef,
    const float* __restrict__ memory, const float* __restrict__ last_update,
    const bf16* __restrict__ wb,
    const float* __restrict__ b_edge, const float* __restrict__ b_mp1,
    const float* __restrict__ b_mp2, const float* __restrict__ b_ih,
    const float* __restrict__ b_hh,
    int* __restrict__ occS, int* __restrict__ occD,
    bf16* __restrict__ procB, float* __restrict__ newmemS)
{
    __shared__ bf16 A0[32 * 200];   // edge feats; per-wave slab later reused as A2 [16][136]
    __shared__ bf16 A1[32 * 136];   // edge_emb; per-wave slab later reused as Ap [16][136]
    __shared__ bf16 Ac[32 * 136];   // decayed cur (bf16 for MFMA)
    int tid = threadIdx.x;
    long row0 = (long)blockIdx.x * 32;
    if (tid < 32) {   // last-occurrence tags for both rounds (occ tables inited in prep)
        int rid = (int)row0 + tid;
        atomicMax(&occS[clampid(src_ids[rid])], rid);
        atomicMax(&occD[clampid(dst_ids[rid])], rid);
    }
    int w = tid >> 6, lane = tid & 63, p = lane & 15, q = lane >> 4;
    int r0 = w * 16;
    // stage A0 (wave-local): 16 rows x 172 f32 -> bf16, zero-pad to 192
    const float4* ef = (const float4*)edgef;
    for (int i = lane; i < 16 * 43; i += 64) {
        int r = i / 43, c4 = i - r * 43;
        float4 v = ef[(row0 + r0 + r) * 43 + c4];
        bf16* d = &A0[(r0 + r) * 200 + c4 * 4];
        d[0] = (bf16)v.x; d[1] = (bf16)v.y; d[2] = (bf16)v.z; d[3] = (bf16)v.w;
    }
    for (int i = lane; i < 16 * 20; i += 64) {
        int r = i / 20, c = i - r * 20;
        A0[(r0 + r) * 200 + 172 + c] = (bf16)0.f;
    }
    wavefence();
    f32x4 acc[8];
    // GEMM1: edge_emb, K=192 -> A1
    for (int j = 0; j < 8; ++j) acc[j] = (f32x4){0.f, 0.f, 0.f, 0.f};
    gemm_wave<8, 6>(A0 + r0 * 200, 200, wb + W_EDGE_O, 192, acc);
    for (int j = 0; j < 8; ++j) {
        int col = j * 16 + p; float bb = b_edge[col];
#pragma unroll
        for (int v = 0; v < 4; ++v) A1[(r0 + q * 4 + v) * 136 + col] = (bf16)(acc[j][v] + bb);
    }
    wavefence();
    // GEMM2 + relu: K=128 -> myA2 (overlay in this wave's A0 slab)
    for (int j = 0; j < 8; ++j) acc[j] = (f32x4){0.f, 0.f, 0.f, 0.f};
    gemm_wave<8, 4>(A1 + r0 * 136, 136, wb + W_MP1_O, 128, acc);
    bf16* myA2 = A0 + r0 * 200;
    for (int j = 0; j < 8; ++j) {
        int col = j * 16 + p; float bb = b_mp1[col];
#pragma unroll
        for (int v = 0; v < 4; ++v) myA2[(q * 4 + v) * 136 + col] = (bf16)fmaxf(acc[j][v] + bb, 0.f);
    }
    wavefence();
    // GEMM3: proc, K=128 -> myAp (overlay in this wave's A1 slab) + procB (for dst round)
    for (int j = 0; j < 8; ++j) acc[j] = (f32x4){0.f, 0.f, 0.f, 0.f};
    gemm_wave<8, 4>(myA2, 136, wb + W_MP2_O, 128, acc);
    bf16* myAp = A1 + r0 * 136;
    for (int j = 0; j < 8; ++j) {
        int col = j * 16 + p; float bb = b_mp2[col];
#pragma unroll
        for (int v = 0; v < 4; ++v) {
            float pv = acc[j][v] + bb;
            myAp[(q * 4 + v) * 136 + col] = (bf16)pv;
            procB[(row0 + r0 + q * 4 + v) * MEMD + col] = (bf16)pv;
        }
    }
    // stage Ac: gather pristine memory, decay (round 0 reads pre-update state)
    for (int i = lane; i < 256; i += 64) {
        int r = i >> 4, c8 = i & 15;
        int rid = (int)row0 + r0 + r;
        int id = clampid(src_ids[rid]);
        float lu = last_update[id];
        float s = __expf(-0.1f * fmaxf(ts[rid] - lu, 0.f));
        const float* rp = memory + (long)id * MEMD + c8 * 8;
        f32x4 v0 = *(const f32x4*)rp;
        f32x4 v1 = *(const f32x4*)(rp + 4);
        bf16x8 cb;
        cb[0] = (bf16)(v0.x * s); cb[1] = (bf16)(v0.y * s);
        cb[2] = (bf16)(v0.z * s); cb[3] = (bf16)(v0.w * s);
        cb[4] = (bf16)(v1.x * s); cb[5] = (bf16)(v1.y * s);
        cb[6] = (bf16)(v1.z * s); cb[7] = (bf16)(v1.w * s);
        *(bf16x8*)&Ac[(r0 + r) * 136 + c8 * 8] = cb;
    }
    wavefence();
    // per-output-row h (f32, from L1/L2-hot memory rows)
    const float* hrow[4]; float s4[4];
#pragma unroll
    for (int v = 0; v < 4; ++v) {
        int rid = (int)row0 + r0 + q * 4 + v;
        int id = clampid(src_ids[rid]);
        float lu = last_update[id];
        s4[v] = __expf(-0.1f * fmaxf(ts[rid] - lu, 0.f));
        hrow[v] = memory + (long)id * MEMD;
    }
    gru_tiles<4>(myAp, Ac + r0 * 136, 136, wb + W_IH_O, wb + W_HH_O,
                 b_ih, b_hh, hrow, s4, newmemS + (row0 + r0) * MEMD);
}

// ---------------- dst-round GRU: gather through occS/newmemS indirection; barrier-free ----------------
__global__ __launch_bounds__(128) void grud_kernel(
    const int* __restrict__ dst_ids, const float* __restrict__ ts,
    const bf16* __restrict__ procB, const float* __restrict__ memory,
    const float* __restrict__ last_update, const int* __restrict__ occS,
    const float* __restrict__ newmemS, const bf16* __restrict__ wb,
    const float* __restrict__ b_ih, const float* __restrict__ b_hh,
    float* __restrict__ newmemD)
{
    __shared__ bf16 Ap[32 * 136];
    __shared__ bf16 Ac[32 * 136];
    int tid = threadIdx.x;
    long row0 = (long)blockIdx.x * 32;
    int w = tid >> 6, lane = tid & 63, p = lane & 15, q = lane >> 4;
    int r0 = w * 16;
    for (int i = lane; i < 256; i += 64) {
        int r = i >> 4, c8 = i & 15;
        *(bf16x8*)&Ap[(r0 + r) * 136 + c8 * 8] =
            *(const bf16x8*)&procB[(row0 + r0 + r) * MEMD + c8 * 8];
    }
    for (int i = lane; i < 256; i += 64) {
        int r = i >> 4, c8 = i & 15;
        int rid = (int)row0 + r0 + r;
        int id = clampid(dst_ids[rid]);
        int tg = occS[id];
        const float* rp; float lu;
        if (tg >= 0) { rp = newmemS + (long)tg * MEMD; lu = ts[tg]; }
        else         { rp = memory + (long)id * MEMD;  lu = last_update[id]; }
        float s = __expf(-0.1f * fmaxf(ts[rid] - lu, 0.f));
        const float* rpp = rp + c8 * 8;
        f32x4 v0 = *(const f32x4*)rpp;
        f32x4 v1 = *(const f32x4*)(rpp + 4);
        bf16x8 cb;
        cb[0] = (bf16)(v0.x * s); cb[1] = (bf16)(v0.y * s);
        cb[2] = (bf16)(v0.z * s); cb[3] = (bf16)(v0.w * s);
        cb[4] = (bf16)(v1.x * s); cb[5] = (bf16)(v1.y * s);
        cb[6] = (bf16)(v1.z * s); cb[7] = (bf16)(v1.w * s);
        *(bf16x8*)&Ac[(r0 + r) * 136 + c8 * 8] = cb;
    }
    wavefence();
    const float* hrow[4]; float s4[4];
#pragma unroll
    for (int v = 0; v < 4; ++v) {
        int rid = (int)row0 + r0 + q * 4 + v;
        int id = clampid(dst_ids[rid]);
        int tg = occS[id];
        const float* rp; float lu;
        if (tg >= 0) { rp = newmemS + (long)tg * MEMD; lu = ts[tg]; }
        else         { rp = memory + (long)id * MEMD;  lu = last_update[id]; }
        s4[v] = __expf(-0.1f * fmaxf(ts[rid] - lu, 0.f));
        hrow[v] = rp;
    }
    gru_tiles<4>(Ap + r0 * 136, Ac + r0 * 136, 136, wb + W_IH_O, wb + W_HH_O,
                 b_ih, b_hh, hrow, s4, newmemD + (row0 + r0) * MEMD);
}

// ---------------- fused embeddings (both sides) + link predictor; barrier-free ----------------
__global__ __launch_bounds__(128) void embl_kernel(
    const int* __restrict__ src_ids, const int* __restrict__ dst_ids,
    const float* __restrict__ src_feat, const float* __restrict__ dst_feat,
    const float* __restrict__ ts, const float* __restrict__ memory,
    const float* __restrict__ last_update, const int* __restrict__ occS,
    const int* __restrict__ occD, const float* __restrict__ newmemS,
    const float* __restrict__ newmemD, const bf16* __restrict__ wb,
    const float* __restrict__ b_node, const float* __restrict__ b_p1,
    const float* __restrict__ b_p2, const float* __restrict__ b_l1,
    const float* __restrict__ W_l2, const float* __restrict__ b_l2,
    float* __restrict__ dout)
{
    __shared__ bf16 A0[32 * 200];    // feats; per-wave slab reused as A2 [16][136]
    __shared__ bf16 Comb[32 * 264];  // [attended | node_emb]
    __shared__ bf16 E[32 * 264];     // [embS | embD]
    int tid = threadIdx.x;
    long row0 = (long)blockIdx.x * 32;
    int w = tid >> 6, lane = tid & 63, p = lane & 15, q = lane >> 4;
    int r0 = w * 16;
    f32x4 acc[8];
    for (int side = 0; side < 2; ++side) {
        const int* ids = side ? dst_ids : src_ids;
        const float4* ft = (const float4*)(side ? dst_feat : src_feat);
        wavefence();  // prior side's myA2/Comb reads precede this side's restaging
        for (int i = lane; i < 16 * 43; i += 64) {
            int r = i / 43, c4 = i - r * 43;
            float4 v = ft[(row0 + r0 + r) * 43 + c4];
            bf16* d = &A0[(r0 + r) * 200 + c4 * 4];
            d[0] = (bf16)v.x; d[1] = (bf16)v.y; d[2] = (bf16)v.z; d[3] = (bf16)v.w;
        }
        for (int i = lane; i < 16 * 20; i += 64) {
            int r = i / 20, c = i - r * 20;
            A0[(r0 + r) * 200 + 172 + c] = (bf16)0.f;
        }
        // attended = mem_row * score^2 -> Comb cols 0..127; also emit score output
        for (int i = lane; i < 256; i += 64) {
            int r = i >> 4, c8 = i & 15;
            int rid = (int)row0 + r0 + r;
            int id = clampid(ids[rid]);
            int tgD = occD[id], tgS = occS[id];
            const float* rp; float lu;
            if (tgD >= 0)      { rp = newmemD + (long)tgD * MEMD; lu = ts[tgD]; }
            else if (tgS >= 0) { rp = newmemS + (long)tgS * MEMD; lu = ts[tgS]; }
            else               { rp = memory + (long)id * MEMD;   lu = last_update[id]; }
            float sc = __expf(-0.1f * fmaxf(ts[rid] - lu, 0.f));
            if (c8 == 0) dout[B_ROWS + side * B_ROWS + rid] = sc;
            float ss = sc * sc;
            const float* rpp = rp + c8 * 8;
            f32x4 v0 = *(const f32x4*)rpp;
            f32x4 v1 = *(const f32x4*)(rpp + 4);
            bf16x8 cb;
            cb[0] = (bf16)(v0.x * ss); cb[1] = (bf16)(v0.y * ss);
            cb[2] = (bf16)(v0.z * ss); cb[3] = (bf16)(v0.w * ss);
            cb[4] = (bf16)(v1.x * ss); cb[5] = (bf16)(v1.y * ss);
            cb[6] = (bf16)(v1.z * ss); cb[7] = (bf16)(v1.w * ss);
            *(bf16x8*)&Comb[(r0 + r) * 264 + c8 * 8] = cb;
        }
        wavefence();
        // node_emb GEMM: K=192 -> Comb cols 128..255
        for (int j = 0; j < 8; ++j) acc[j] = (f32x4){0.f, 0.f, 0.f, 0.f};
        gemm_wave<8, 6>(A0 + r0 * 200, 200, wb + W_NODE_O, 192, acc);
        for (int j = 0; j < 8; ++j) {
            int col = j * 16 + p; float bb = b_node[col];
#pragma unroll
            for (int v = 0; v < 4; ++v)
                Comb[(r0 + q * 4 + v) * 264 + 128 + col] = (bf16)(acc[j][v] + bb);
        }
        wavefence();
        // p1 GEMM: K=256, relu -> myA2 (overlay in this wave's A0 slab)
        for (int j = 0; j < 8; ++j) acc[j] = (f32x4){0.f, 0.f, 0.f, 0.f};
        gemm_wave<8, 8>(Comb + r0 * 264, 264, wb + W_P1_O, 256, acc);
        bf16* myA2 = A0 + r0 * 200;
        for (int j = 0; j < 8; ++j) {
            int col = j * 16 + p; float bb = b_p1[col];
#pragma unroll
            for (int v = 0; v < 4; ++v)
                myA2[(q * 4 + v) * 136 + col] = (bf16)fmaxf(acc[j][v] + bb, 0.f);
        }
        wavefence();
        // p2 GEMM: K=128 -> E cols side*128..side*128+127
        for (int j = 0; j < 8; ++j) acc[j] = (f32x4){0.f, 0.f, 0.f, 0.f};
        gemm_wave<8, 4>(myA2, 136, wb + W_P2_O, 128, acc);
        for (int j = 0; j < 8; ++j) {
            int col = j * 16 + p; float bb = b_p2[col];
#pragma unroll
            for (int v = 0; v < 4; ++v)
                E[(r0 + q * 4 + v) * 264 + side * 128 + col] = (bf16)(acc[j][v] + bb);
        }
    }
    wavefence();
    // link l1 GEMM: K=256; then in-register relu-dot with W_l2 + shfl reduce
    for (int j = 0; j < 8; ++j) acc[j] = (f32x4){0.f, 0.f, 0.f, 0.f};
    gemm_wave<8, 8>(E + r0 * 264, 264, wb + W_L1_O, 256, acc);
    float part[4] = {0.f, 0.f, 0.f, 0.f};
#pragma unroll
    for (int j = 0; j < 8; ++j) {
        int col = j * 16 + p;
        float bb = b_l1[col];
        float wl = W_l2[col];
#pragma unroll
        for (int v = 0; v < 4; ++v) part[v] += fmaxf(acc[j][v] + bb, 0.f) * wl;
    }
#pragma unroll
    for (int m = 1; m < 16; m <<= 1) {
#pragma unroll
        for (int v = 0; v < 4; ++v) part[v] += __shfl_xor(part[v], m);
    }
    if (p == 0) {
        float bl = b_l2[0];
#pragma unroll
        for (int v = 0; v < 4; ++v)
            dout[row0 + r0 + q * 4 + v] = sigmoidf_(part[v] + bl);
    }
}

extern "C" void kernel_launch(void* const* d_in, const int* in_sizes, int n_in,
                              void* d_out, int out_size, void* d_ws, size_t ws_size,
                              hipStream_t stream)
{
    const int*   src_ids  = (const int*)d_in[0];
    const int*   dst_ids  = (const int*)d_in[1];
    const float* src_feat = (const float*)d_in[2];
    const float* dst_feat = (const float*)d_in[3];
    const float* ts       = (const float*)d_in[4];
    const float* edgef    = (const float*)d_in[5];
    const float* memory   = (const float*)d_in[6];     // read-only (COW)
    const float* last_update = (const float*)d_in[7];  // read-only
    const float* W_edge = (const float*)d_in[8],  *b_edge = (const float*)d_in[9];
    const float* W_mp1  = (const float*)d_in[10], *b_mp1  = (const float*)d_in[11];
    const float* W_mp2  = (const float*)d_in[12], *b_mp2  = (const float*)d_in[13];
    const float* W_ih   = (const float*)d_in[14], *W_hh   = (const float*)d_in[15];
    const float* b_ih   = (const float*)d_in[16], *b_hh   = (const float*)d_in[17];
    const float* W_node = (const float*)d_in[18], *b_node = (const float*)d_in[19];
    const float* W_p1   = (const float*)d_in[20], *b_p1   = (const float*)d_in[21];
    const float* W_p2   = (const float*)d_in[22], *b_p2   = (const float*)d_in[23];
    const float* W_l1   = (const float*)d_in[24], *b_l1   = (const float*)d_in[25];
    const float* W_l2   = (const float*)d_in[26], *b_l2   = (const float*)d_in[27];

    char* ws = (char*)d_ws;
    int*   occS     = (int*)ws;                        // 4,000,000 B
    int*   occD     = (int*)(ws + 4000000);            // 4,000,000 B
    bf16*  wb       = (bf16*)(ws + 8000000);           // 524,288 B
    bf16*  procB    = (bf16*)(ws + 8524288);           // 4 MiB
    float* newmemS  = (float*)(ws + 12718592);         // 8 MiB
    float* newmemD  = (float*)(ws + 21107200);         // 8 MiB
    float* dout     = (float*)d_out;

    prep_kernel<<<1024, 256, 0, stream>>>(W_edge, W_mp1, W_mp2, W_ih, W_hh,
                                          W_node, W_p1, W_p2, W_l1, occS, occD, wb);
    // fused tagging + proc + src-round GRU (reads pristine memory)
    pgs_kernel<<<512, 128, 0, stream>>>(src_ids, dst_ids, ts, edgef, memory, last_update,
                                        wb, b_edge, b_mp1, b_mp2, b_ih, b_hh,
                                        occS, occD, procB, newmemS);
    // dst-round GRU (through occS/newmemS indirection)
    grud_kernel<<<512, 128, 0, stream>>>(dst_ids, ts, procB, memory, last_update,
                                         occS, newmemS, wb, b_ih, b_hh, newmemD);
    // embeddings (both sides) + link predictor, fused
    embl_kernel<<<512, 128, 0, stream>>>(src_ids, dst_ids, src_feat, dst_feat,
                                         ts, memory, last_update, occS, occD,
                                         newmemS, newmemD, wb,
                                         b_node, b_p1, b_p2, b_l1, W_l2, b_l2, dout);
}